// Round 6
// baseline (482.662 us; speedup 1.0000x reference)
//
#include <hip/hip_runtime.h>

// Problem: B=2, S=2048, DIM=2048, H=16, KVH=4, HD=128, WINDOW=1024.
// Score algebra (re-derived r6): reference's rope concat gives
//   score = SCALE*( sum_{d<64} 2*qr_d*kr_d*cos(th_q,d - th_k,d) + sum qi*ki )
// Factorized as 192-dim dot:  Q' = [2SC*qr*cos_q, 2SC*qr*sin_q, SC*qi],
//                             K' = [kr*cos_k,     kr*sin_k,     ki].
// positions & mask are dead (mask == sliding window (q-1024, q]).
// 2SC/SC folded into wq columns at conversion. K' materialized by the KV-GEMM
// epilogue; Q RoPE applied in-register inside k_attn.
//
// Memory: d_out(32MiB) = Q 16 | K' 6 | VT 4 (dead before O-proj rewrites it).
// ws(24MiB) = xb 16 (later attn_out) | 8 MiB weight slot (serial reuse).

typedef __attribute__((ext_vector_type(4))) float f32x4;
typedef __attribute__((ext_vector_type(8))) short s16x8;
typedef __attribute__((ext_vector_type(4))) unsigned short u16x4;

#define DEV static __device__ __forceinline__

DEV unsigned short f2bf(float f) {
  unsigned int u = __float_as_uint(f);
  u += 0x7fffu + ((u >> 16) & 1u);
  return (unsigned short)(u >> 16);
}
DEV float bf2f(unsigned short us) {
  return __uint_as_float(((unsigned int)us) << 16);
}
DEV f32x4 mfma_bf16(s16x8 a, s16x8 b, f32x4 c) {
  return __builtin_amdgcn_mfma_f32_16x16x32_bf16(a, b, c, 0, 0, 0);
}

// ---------------- sentinel (ws too small -> unambiguous signal) ----------------
__global__ void k_sentinel(float* __restrict__ out, int n) {
  int i = blockIdx.x * blockDim.x + threadIdx.x;
  const int stride = gridDim.x * blockDim.x;
  for (; i < n; i += stride) out[i] = 1.0e6f;
}

// ---------------- convert x (f32 -> bf16, flat) ----------------
__global__ void k_cvt_x(const float* __restrict__ x, unsigned short* __restrict__ xb, int n4) {
  int i = blockIdx.x * blockDim.x + threadIdx.x;
  const int stride = gridDim.x * blockDim.x;
  for (; i < n4; i += stride) {
    float4 v = ((const float4*)x)[i];
    u16x4 o = {f2bf(v.x), f2bf(v.y), f2bf(v.z), f2bf(v.w)};
    ((u16x4*)xb)[i] = o;
  }
}

// ------- transpose-convert weights: W[K=2048][N] f32 -> Wt[N][K=2048] bf16 -------
// qscale=1: multiply column n by ((n%128)<64 ? 2*SCALE : SCALE)  (wq only)
__global__ void k_cvt_w(const float* __restrict__ w, unsigned short* __restrict__ wt,
                        int N, int qscale) {
  __shared__ unsigned short tile[64][66];
  const int n0 = blockIdx.x * 64, k0 = blockIdx.y * 64;
  const int t = threadIdx.x;
  const float SC = 0.08838834764831845f;  // 128^-0.5
#pragma unroll
  for (int i = 0; i < 16; ++i) {
    const int idx = i * 256 + t;
    const int r = idx >> 6, c = idx & 63;
    float v = w[(k0 + r) * N + n0 + c];
    if (qscale) v *= ((((n0 + c) & 127) < 64) ? 2.f * SC : SC);
    tile[r][c] = f2bf(v);
  }
  __syncthreads();
#pragma unroll
  for (int i = 0; i < 16; ++i) {
    const int idx = i * 256 + t;
    const int rn = idx >> 6, ck = idx & 63;
    wt[(n0 + rn) * 2048 + k0 + ck] = tile[ck][rn];
  }
}

// ---------------- GEMM, 128x128 tile, BK=32, reg-staged LDS ----------------
// A [M=4096][2048] bf16 row-major; B = Bt[n][2048] bf16 (pre-transposed).
// mode 0: N=2048, epilogue scatters Q[b][h][s][128]
// mode 1: N=1024 (wkt||wvt): n<512 -> K'[b][kv][s][192] with RoPE(cos/sin);
//         n>=512 -> VT[b][kv][d][s]
// mode 2: N=2048, epilogue writes f32 C row-major
__global__ __launch_bounds__(256) void k_gemm(
    const unsigned short* __restrict__ A, const unsigned short* __restrict__ B,
    const int mode, unsigned short* __restrict__ Qo, unsigned short* __restrict__ Kp,
    unsigned short* __restrict__ Vo, float* __restrict__ Co,
    const float* __restrict__ cosp, const float* __restrict__ sinp) {
  __shared__ __align__(16) unsigned short As[4096];  // [128 m][32 k], 64B rows
  __shared__ __align__(16) unsigned short Bs[4096];  // [128 n][32 k]
  char* As_c = (char*)As;
  char* Bs_c = (char*)Bs;
  const int t = threadIdx.x;
  const int lane = t & 63, wid = t >> 6;
  const int l16 = lane & 15, g = lane >> 4;
  const int wr = wid >> 1, wc = wid & 1;
  const int m0 = blockIdx.x * 128, n0 = blockIdx.y * 128;

  const unsigned short* pa = A + (m0 + (t >> 2)) * 2048 + ((t & 3) << 3);
  const unsigned short* pb = B + (n0 + (t >> 2)) * 2048 + ((t & 3) << 3);
  char* la = As_c + t * 16;
  char* lb = Bs_c + t * 16;

  f32x4 acc[4][4] = {};

  for (int kt = 0; kt < 64; ++kt) {
    const unsigned short* pak = pa + kt * 32;
    const unsigned short* pbk = pb + kt * 32;
    s16x8 a0 = *(const s16x8*)(pak);
    s16x8 a1 = *(const s16x8*)(pak + 64 * 2048);
    s16x8 b0 = *(const s16x8*)(pbk);
    s16x8 b1 = *(const s16x8*)(pbk + 64 * 2048);
    __syncthreads();
    *(s16x8*)la = a0;
    *(s16x8*)(la + 4096) = a1;
    *(s16x8*)lb = b0;
    *(s16x8*)(lb + 4096) = b1;
    __syncthreads();
    s16x8 af[4], bfr[4];
#pragma unroll
    for (int i = 0; i < 4; ++i) {
      af[i]  = *(const s16x8*)(As_c + (wr * 64 + i * 16 + l16) * 64 + g * 16);
      bfr[i] = *(const s16x8*)(Bs_c + (wc * 64 + i * 16 + l16) * 64 + g * 16);
    }
#pragma unroll
    for (int i = 0; i < 4; ++i)
#pragma unroll
      for (int j = 0; j < 4; ++j) acc[i][j] = mfma_bf16(af[i], bfr[j], acc[i][j]);
  }

#pragma unroll
  for (int i = 0; i < 4; ++i) {
#pragma unroll
    for (int j = 0; j < 4; ++j) {
#pragma unroll
      for (int r = 0; r < 4; ++r) {
        const float val = acc[i][j][r];
        const int m = m0 + wr * 64 + i * 16 + g * 4 + r;   // C row
        const int n = n0 + wc * 64 + j * 16 + l16;         // C col
        if (mode == 2) {
          Co[m * 2048 + n] = val;
        } else {
          const int bb = m >> 11, s = m & 2047;
          if (mode == 0) {          // Q[b][h][s][d] (RoPE deferred to k_attn)
            const int hh = n >> 7, d = n & 127;
            Qo[((bb * 16 + hh) * 2048 + s) * 128 + d] = f2bf(val);
          } else if (n < 512) {     // K'[b][kv][s][192] with RoPE
            const int kv = n >> 7, d = n & 127;
            unsigned short* kr = Kp + ((bb * 4 + kv) * 2048 + s) * 192;
            if (d < 64) {
              const float c = cosp[s * 64 + d], sn = sinp[s * 64 + d];
              kr[d]      = f2bf(val * c);
              kr[64 + d] = f2bf(val * sn);
            } else {
              kr[64 + d] = f2bf(val);   // e = 128 + (d-64)
            }
          } else {                  // V^T[b][kv][d][s]
            const int n2 = n - 512, kv = n2 >> 7, d = n2 & 127;
            Vo[((bb * 4 + kv) * 128 + d) * 2048 + s] = f2bf(val);
          }
        }
      }
    }
  }
}

// ---------------- windowed flash attention, KVBLK=64, K-dim 192 ----------------
// grid (qt=32, h=16, b=2); 256 threads = 4 waves x 16 q-rows; 64-key tiles.
__global__ __launch_bounds__(256) void k_attn(
    const unsigned short* __restrict__ Qb, const unsigned short* __restrict__ Kpb,
    const unsigned short* __restrict__ VTb, const float* __restrict__ cosp,
    const float* __restrict__ sinp, unsigned short* __restrict__ Ob) {
  __shared__ __align__(16) char Ks[24576];  // [64 key][192 e] bf16, byte^=((key&7)<<4)
  __shared__ __align__(16) char Vs[16384];  // [128 d][64 key] bf16, byte^=((d&7)<<4)
  __shared__ __align__(16) unsigned short Ps[4][1024];  // per-wave P [16 q][64 k]
  const int t = threadIdx.x;
  const int wid = t >> 6, lane = t & 63;
  const int l = lane & 15, g = lane >> 4;
  const int qt = blockIdx.x, h = blockIdx.y, b = blockIdx.z;
  const int kvh = h >> 2;
  const int w0 = qt * 64 + wid * 16;

  // ---- Q load (128-dim) + in-register RoPE -> 192-dim frags ----
  // Q' e-layout: [0,64)=2SC*qr*cos, [64,128)=2SC*qr*sin, [128,192)=SC*qi
  // (2SC/SC already folded into wq). frag c covers e = c*32 + g*8 .. +8.
  const unsigned short* qptr = Qb + ((b * 16 + h) * 2048 + (w0 + l)) * 128;
  s16x8 q0 = *(const s16x8*)(qptr + g * 8);        // qr cols g*8..
  s16x8 q1 = *(const s16x8*)(qptr + 32 + g * 8);   // qr cols 32+g*8..
  s16x8 qf6[6];
  {
    const float* cr = cosp + (w0 + l) * 64 + g * 8;
    const float* sr = sinp + (w0 + l) * 64 + g * 8;
#pragma unroll
    for (int j = 0; j < 8; ++j) {
      const float v0 = bf2f((unsigned short)q0[j]);
      const float v1 = bf2f((unsigned short)q1[j]);
      qf6[0][j] = (short)f2bf(v0 * cr[j]);
      qf6[1][j] = (short)f2bf(v1 * cr[32 + j]);
      qf6[2][j] = (short)f2bf(v0 * sr[j]);
      qf6[3][j] = (short)f2bf(v1 * sr[32 + j]);
    }
  }
  qf6[4] = *(const s16x8*)(qptr + 64 + g * 8);     // qi cols 64+g*8..
  qf6[5] = *(const s16x8*)(qptr + 96 + g * 8);     // qi cols 96+g*8..

  f32x4 O[8] = {};
  float mrow[4] = {-1e30f, -1e30f, -1e30f, -1e30f};
  float lrow[4] = {0.f, 0.f, 0.f, 0.f};

  const unsigned short* kbase = Kpb + (b * 4 + kvh) * (2048 * 192);
  const unsigned short* vbase = VTb + (b * 4 + kvh) * (128 * 2048);

  int kb0 = qt * 64 - 1023;
  if (kb0 < 0) kb0 = 0;
  kb0 &= ~63;
  const int kbend = qt * 64;

  // staging split for K': thread t owns row t>>2, chunk quarter t&3 (6 chunks)
  const int krow = t >> 2, kq = t & 3;

  for (int kb = kb0; kb <= kbend; kb += 64) {
    __syncthreads();  // previous tile's reads done
    {  // stage K' tile: [64 key][192 e], 384B rows
      const unsigned short* ksrc = kbase + (kb + krow) * 192 + kq * 8;
      char* kdst = Ks + krow * 384;
      const int sw = (krow & 7) << 4;
#pragma unroll
      for (int j = 0; j < 6; ++j) {
        s16x8 v = *(const s16x8*)(ksrc + 32 * j);
        *(s16x8*)(kdst + ((kq * 16 + 64 * j) ^ sw)) = v;
      }
    }
#pragma unroll
    for (int p = 0; p < 4; ++p) {  // stage V^T tile: [128 d][64 key]
      const int o = (p * 256 + t) * 16;
      const int d = o >> 7, cb = o & 127;
      s16x8 v = *(const s16x8*)(vbase + d * 2048 + kb + (cb >> 1));
      *(s16x8*)(Vs + d * 128 + (cb ^ ((d & 7) << 4))) = v;
    }
    __syncthreads();
    if (kb + 63 < w0 - 1023 || kb > w0 + 15) continue;  // wave-uniform skip
    const bool interior = (kb >= w0 - 1008) && (kb + 63 <= w0);

    // QK^T: D[q][key], four 16-key groups, K = 192 (6 MFMA each)
    f32x4 sc[4];
#pragma unroll
    for (int hf = 0; hf < 4; ++hf) {
      f32x4 acc = {0.f, 0.f, 0.f, 0.f};
      const int key = hf * 16 + l;
      const char* kr = Ks + key * 384;
      const int sw = (key & 7) << 4;
#pragma unroll
      for (int c = 0; c < 6; ++c) {
        s16x8 kf = *(const s16x8*)(kr + ((c * 64 + g * 16) ^ sw));
        acc = mfma_bf16(qf6[c], kf, acc);
      }
      sc[hf] = acc;
    }

    // online softmax (row q = w0 + g*4 + r; keys = kb + hf*16 + l)
#pragma unroll
    for (int r = 0; r < 4; ++r) {
      const int q = w0 + g * 4 + r;
      float s0 = sc[0][r], s1 = sc[1][r], s2 = sc[2][r], s3 = sc[3][r];
      if (!interior) {
        const int kg = kb + l;
        if (kg      > q || kg      <= q - 1024) s0 = -1e30f;
        if (kg + 16 > q || kg + 16 <= q - 1024) s1 = -1e30f;
        if (kg + 32 > q || kg + 32 <= q - 1024) s2 = -1e30f;
        if (kg + 48 > q || kg + 48 <= q - 1024) s3 = -1e30f;
      }
      float mx = fmaxf(fmaxf(s0, s1), fmaxf(s2, s3));
      mx = fmaxf(mx, __shfl_xor(mx, 1));
      mx = fmaxf(mx, __shfl_xor(mx, 2));
      mx = fmaxf(mx, __shfl_xor(mx, 4));
      mx = fmaxf(mx, __shfl_xor(mx, 8));
      const float mn = fmaxf(mrow[r], mx);
      const float al = __expf(mrow[r] - mn);
      const float p0 = __expf(s0 - mn), p1 = __expf(s1 - mn);
      const float p2 = __expf(s2 - mn), p3 = __expf(s3 - mn);
      float rs = (p0 + p1) + (p2 + p3);
      rs += __shfl_xor(rs, 1);
      rs += __shfl_xor(rs, 2);
      rs += __shfl_xor(rs, 4);
      rs += __shfl_xor(rs, 8);
      lrow[r] = lrow[r] * al + rs;
      mrow[r] = mn;
#pragma unroll
      for (int d2 = 0; d2 < 8; ++d2) O[d2][r] *= al;
      unsigned short* prow = &Ps[wid][(g * 4 + r) * 64];
      prow[l]      = f2bf(p0);
      prow[l + 16] = f2bf(p1);
      prow[l + 32] = f2bf(p2);
      prow[l + 48] = f2bf(p3);
    }

    // PV: A = P (per-wave LDS round-trip), B = V^T tile, two K=32 halves
    const s16x8 pf0 = *(const s16x8*)(&Ps[wid][l * 64 + g * 8]);
    const s16x8 pf1 = *(const s16x8*)(&Ps[wid][l * 64 + 32 + g * 8]);
#pragma unroll
    for (int d2 = 0; d2 < 8; ++d2) {
      const int d = d2 * 16 + l;
      const int sw = (d & 7) << 4;
      s16x8 vf0 = *(const s16x8*)(Vs + d * 128 + ((g * 16) ^ sw));
      s16x8 vf1 = *(const s16x8*)(Vs + d * 128 + ((64 + g * 16) ^ sw));
      O[d2] = mfma_bf16(pf0, vf0, O[d2]);
      O[d2] = mfma_bf16(pf1, vf1, O[d2]);
    }
  }

#pragma unroll
  for (int r = 0; r < 4; ++r) {
    const float inv = 1.0f / lrow[r];
    const int m = b * 2048 + w0 + g * 4 + r;
    unsigned short* orow = Ob + m * 2048 + h * 128;
#pragma unroll
    for (int d2 = 0; d2 < 8; ++d2) orow[d2 * 16 + l] = f2bf(O[d2][r] * inv);
  }
}

extern "C" void kernel_launch(void* const* d_in, const int* in_sizes, int n_in,
                              void* d_out, int out_size, void* d_ws, size_t ws_size,
                              hipStream_t stream) {
  (void)in_sizes; (void)n_in; (void)out_size;
  const float* x    = (const float*)d_in[0];
  const float* cosp = (const float*)d_in[1];
  const float* sinp = (const float*)d_in[2];
  // d_in[3]=positions, d_in[4]=mask: dead
  const float* wq = (const float*)d_in[5];
  const float* wk = (const float*)d_in[6];
  const float* wv = (const float*)d_in[7];
  const float* wo = (const float*)d_in[8];
  float* out = (float*)d_out;

  if (ws_size < 25165824u) {
    k_sentinel<<<2048, 256, 0, stream>>>(out, 8388608);
    return;
  }

  char* ws = (char*)d_ws;
  unsigned short* xb  = (unsigned short*)(ws);             // 16 MiB; later attn_out
  unsigned short* wsl = (unsigned short*)(ws + 16777216);  // 8 MiB weight slot

  // d_out scratch: Q 16 MiB | K' 6 MiB | VT 4 MiB  (<= 26 MiB of 32)
  char* oc = (char*)d_out;
  unsigned short* Qb  = (unsigned short*)(oc);             // [2][16][2048][128]
  unsigned short* Kp  = (unsigned short*)(oc + 16777216);  // [2][4][2048][192]
  unsigned short* VTb = (unsigned short*)(oc + 23068672);  // [2][4][128][2048]

  k_cvt_x<<<2048, 256, 0, stream>>>(x, xb, 2097152);
  // wq -> slot (with 2SC/SC fold); Q-GEMM
  k_cvt_w<<<dim3(32, 32), 256, 0, stream>>>(wq, wsl, 2048, 1);
  k_gemm<<<dim3(32, 16), 256, 0, stream>>>(xb, wsl, 0, Qb, Kp, VTb, nullptr,
                                           cosp, sinp);
  // wk|wv -> slot; KV-GEMM (K' gets RoPE in epilogue)
  k_cvt_w<<<dim3(8, 32), 256, 0, stream>>>(wk, wsl, 512, 0);
  k_cvt_w<<<dim3(8, 32), 256, 0, stream>>>(wv, wsl + 1048576, 512, 0);
  k_gemm<<<dim3(32, 8), 256, 0, stream>>>(xb, wsl, 1, Qb, Kp, VTb, nullptr,
                                          cosp, sinp);
  // wo -> slot; attention (attn_out overwrites dead xb); O-proj
  k_cvt_w<<<dim3(32, 32), 256, 0, stream>>>(wo, wsl, 2048, 0);
  k_attn<<<dim3(32, 16, 2), 256, 0, stream>>>(Qb, Kp, VTb, cosp, sinp, xb);
  k_gemm<<<dim3(32, 16), 256, 0, stream>>>(xb, wsl, 2, nullptr, nullptr, nullptr,
                                           out, nullptr, nullptr);
}

// Round 7
// 409.057 us; speedup vs baseline: 1.1799x; 1.1799x over previous
//
#include <hip/hip_runtime.h>

// Problem: B=2, S=2048, DIM=2048, H=16, KVH=4, HD=128, WINDOW=1024.
// score = SCALE*( sum_{d<64} 2*qr_d*kr_d*cos(th_q,d - th_k,d) + sum qi*ki )
// as 192-dim dot: Q' = [2SC*qr*cos_q, 2SC*qr*sin_q, SC*qi], K' = [kr*cos_k,
// kr*sin_k, ki]. positions & mask dead (mask == sliding window (q-1024, q]).
// k_attn (r7 redesign): 32x32 MFMA, swapped QK^T (D[key][q]) and swapped PV
// (D[d][q]) -> softmax fully lane-local for q-row = lane&31; sigma-permuted
// (key bits 2<->3) V reads make P fragments consecutive own-lane registers.
// T14 reg-prefetch: next tile's global loads issued before current compute.
//
// Memory: d_out(32MiB) = Q 16 | K' 6 | VT 4 (dead before O-proj rewrites it).
// ws(24MiB) = xb 16 (later attn_out) | 8 MiB weight slot (serial reuse).

typedef __attribute__((ext_vector_type(4))) float f32x4;
typedef __attribute__((ext_vector_type(16))) float f32x16;
typedef __attribute__((ext_vector_type(8))) short s16x8;
typedef __attribute__((ext_vector_type(4))) short s16x4;
typedef __attribute__((ext_vector_type(4))) unsigned short u16x4;

#define DEV static __device__ __forceinline__

DEV unsigned short f2bf(float f) {
  unsigned int u = __float_as_uint(f);
  u += 0x7fffu + ((u >> 16) & 1u);
  return (unsigned short)(u >> 16);
}
DEV float bf2f(unsigned short us) {
  return __uint_as_float(((unsigned int)us) << 16);
}
DEV f32x4 mfma_bf16(s16x8 a, s16x8 b, f32x4 c) {
  return __builtin_amdgcn_mfma_f32_16x16x32_bf16(a, b, c, 0, 0, 0);
}
DEV f32x16 mfma32(s16x8 a, s16x8 b, f32x16 c) {
  return __builtin_amdgcn_mfma_f32_32x32x16_bf16(a, b, c, 0, 0, 0);
}

// ---------------- sentinel (ws too small -> unambiguous signal) -------------
__global__ void k_sentinel(float* __restrict__ out, int n) {
  int i = blockIdx.x * blockDim.x + threadIdx.x;
  const int stride = gridDim.x * blockDim.x;
  for (; i < n; i += stride) out[i] = 1.0e6f;
}

// ---------------- convert x (f32 -> bf16, flat) ----------------
__global__ void k_cvt_x(const float* __restrict__ x, unsigned short* __restrict__ xb, int n4) {
  int i = blockIdx.x * blockDim.x + threadIdx.x;
  const int stride = gridDim.x * blockDim.x;
  for (; i < n4; i += stride) {
    float4 v = ((const float4*)x)[i];
    u16x4 o = {f2bf(v.x), f2bf(v.y), f2bf(v.z), f2bf(v.w)};
    ((u16x4*)xb)[i] = o;
  }
}

// ------- transpose-convert weights: W[K=2048][N] f32 -> Wt[N][K] bf16 -------
__global__ void k_cvt_w(const float* __restrict__ w, unsigned short* __restrict__ wt,
                        int N, int qscale) {
  __shared__ unsigned short tile[64][66];
  const int n0 = blockIdx.x * 64, k0 = blockIdx.y * 64;
  const int t = threadIdx.x;
  const float SC = 0.08838834764831845f;  // 128^-0.5
#pragma unroll
  for (int i = 0; i < 16; ++i) {
    const int idx = i * 256 + t;
    const int r = idx >> 6, c = idx & 63;
    float v = w[(k0 + r) * N + n0 + c];
    if (qscale) v *= ((((n0 + c) & 127) < 64) ? 2.f * SC : SC);
    tile[r][c] = f2bf(v);
  }
  __syncthreads();
#pragma unroll
  for (int i = 0; i < 16; ++i) {
    const int idx = i * 256 + t;
    const int rn = idx >> 6, ck = idx & 63;
    wt[(n0 + rn) * 2048 + k0 + ck] = tile[ck][rn];
  }
}

// ---------------- GEMM, 128x128 tile, BK=32, reg-staged LDS ----------------
// mode 0: N=2048 -> Q[b][h][s][128]; mode 1: N=1024 -> K'[..][192]+RoPE | VT;
// mode 2: N=2048 -> f32 C row-major.
__global__ __launch_bounds__(256) void k_gemm(
    const unsigned short* __restrict__ A, const unsigned short* __restrict__ B,
    const int mode, unsigned short* __restrict__ Qo, unsigned short* __restrict__ Kp,
    unsigned short* __restrict__ Vo, float* __restrict__ Co,
    const float* __restrict__ cosp, const float* __restrict__ sinp) {
  __shared__ __align__(16) unsigned short As[4096];  // [128 m][32 k]
  __shared__ __align__(16) unsigned short Bs[4096];  // [128 n][32 k]
  char* As_c = (char*)As;
  char* Bs_c = (char*)Bs;
  const int t = threadIdx.x;
  const int lane = t & 63, wid = t >> 6;
  const int l16 = lane & 15, g = lane >> 4;
  const int wr = wid >> 1, wc = wid & 1;
  const int m0 = blockIdx.x * 128, n0 = blockIdx.y * 128;

  const unsigned short* pa = A + (m0 + (t >> 2)) * 2048 + ((t & 3) << 3);
  const unsigned short* pb = B + (n0 + (t >> 2)) * 2048 + ((t & 3) << 3);
  char* la = As_c + t * 16;
  char* lb = Bs_c + t * 16;

  f32x4 acc[4][4] = {};

  for (int kt = 0; kt < 64; ++kt) {
    const unsigned short* pak = pa + kt * 32;
    const unsigned short* pbk = pb + kt * 32;
    s16x8 a0 = *(const s16x8*)(pak);
    s16x8 a1 = *(const s16x8*)(pak + 64 * 2048);
    s16x8 b0 = *(const s16x8*)(pbk);
    s16x8 b1 = *(const s16x8*)(pbk + 64 * 2048);
    __syncthreads();
    *(s16x8*)la = a0;
    *(s16x8*)(la + 4096) = a1;
    *(s16x8*)lb = b0;
    *(s16x8*)(lb + 4096) = b1;
    __syncthreads();
    s16x8 af[4], bfr[4];
#pragma unroll
    for (int i = 0; i < 4; ++i) {
      af[i]  = *(const s16x8*)(As_c + (wr * 64 + i * 16 + l16) * 64 + g * 16);
      bfr[i] = *(const s16x8*)(Bs_c + (wc * 64 + i * 16 + l16) * 64 + g * 16);
    }
#pragma unroll
    for (int i = 0; i < 4; ++i)
#pragma unroll
      for (int j = 0; j < 4; ++j) acc[i][j] = mfma_bf16(af[i], bfr[j], acc[i][j]);
  }

#pragma unroll
  for (int i = 0; i < 4; ++i) {
#pragma unroll
    for (int j = 0; j < 4; ++j) {
#pragma unroll
      for (int r = 0; r < 4; ++r) {
        const float val = acc[i][j][r];
        const int m = m0 + wr * 64 + i * 16 + g * 4 + r;
        const int n = n0 + wc * 64 + j * 16 + l16;
        if (mode == 2) {
          Co[m * 2048 + n] = val;
        } else {
          const int bb = m >> 11, s = m & 2047;
          if (mode == 0) {
            const int hh = n >> 7, d = n & 127;
            Qo[((bb * 16 + hh) * 2048 + s) * 128 + d] = f2bf(val);
          } else if (n < 512) {
            const int kv = n >> 7, d = n & 127;
            unsigned short* kr = Kp + ((bb * 4 + kv) * 2048 + s) * 192;
            if (d < 64) {
              const float c = cosp[s * 64 + d], sn = sinp[s * 64 + d];
              kr[d]      = f2bf(val * c);
              kr[64 + d] = f2bf(val * sn);
            } else {
              kr[64 + d] = f2bf(val);
            }
          } else {
            const int n2 = n - 512, kv = n2 >> 7, d = n2 & 127;
            Vo[((bb * 4 + kv) * 128 + d) * 2048 + s] = f2bf(val);
          }
        }
      }
    }
  }
}

// ------- windowed flash attention: 32x32 MFMA, swapped QK & PV, KVBLK=64 ----
// grid (qt=16, h=16, b=2); 256 threads = 4 waves x 32 q-rows (128/block).
__global__ __launch_bounds__(256, 2) void k_attn(
    const unsigned short* __restrict__ Qb, const unsigned short* __restrict__ Kpb,
    const unsigned short* __restrict__ VTb, const float* __restrict__ cosp,
    const float* __restrict__ sinp, unsigned short* __restrict__ Ob) {
  __shared__ __align__(16) char Ks[24576];  // [64 key][384B], byte^=((key&7)<<4)
  __shared__ __align__(16) char Vs[16384];  // [128 d][128B],  byte^=((d&7)<<4)
  const int t = threadIdx.x;
  const int wid = t >> 6, lane = t & 63;
  const int l5 = lane & 31, g2 = lane >> 5;
  const int qt = blockIdx.x, h = blockIdx.y, b = blockIdx.z;
  const int kvh = h >> 2;
  const int qb0 = qt * 128;
  const int w0 = qb0 + wid * 32;
  const int qrow = w0 + l5;

  // ---- Q' frags: 12 x 8 bf16; frag ec covers e = ec*16 + g2*8 + j ----
  const unsigned short* qp = Qb + ((b * 16 + h) * 2048 + qrow) * 128;
  const float* crow_ = cosp + qrow * 64;
  const float* srow_ = sinp + qrow * 64;
  s16x8 qf[12];
#pragma unroll
  for (int ec = 0; ec < 4; ++ec) {
    const int i0 = ec * 16 + g2 * 8;
    s16x8 qr = *(const s16x8*)(qp + i0);
    s16x8 fc, fs;
#pragma unroll
    for (int j = 0; j < 8; ++j) {
      const float v = bf2f((unsigned short)qr[j]);
      fc[j] = (short)f2bf(v * crow_[i0 + j]);
      fs[j] = (short)f2bf(v * srow_[i0 + j]);
    }
    qf[ec] = fc;
    qf[ec + 4] = fs;
    qf[ec + 8] = *(const s16x8*)(qp + 64 + i0);  // qi
  }

  f32x16 O[4] = {};                 // O[d = db*32 + crow(reg,g2)][q = l5]
  float m_r = -1e30f, l_r = 0.f;    // per-lane state for q-row l5 (own row!)

  const unsigned short* kbase = Kpb + (b * 4 + kvh) * (2048 * 192);
  const unsigned short* vbase = VTb + (b * 4 + kvh) * (128 * 2048);

  int kb0 = qb0 - 1023;
  if (kb0 < 0) kb0 = 0;
  kb0 &= ~63;
  const int kbend = qb0 + 64;
  const int nt = ((kbend - kb0) >> 6) + 1;

  const int krow = t >> 2, kq = t & 3;  // K' staging: 4 threads/row, 6 chunks
  s16x8 kpre[6], vpre[4];

#define LOADK(KB)                                                              \
  {                                                                            \
    const unsigned short* ksrc = kbase + ((KB) + krow) * 192 + kq * 8;         \
    _Pragma("unroll") for (int j = 0; j < 6; ++j)                              \
        kpre[j] = *(const s16x8*)(ksrc + 32 * j);                              \
    _Pragma("unroll") for (int p = 0; p < 4; ++p) {                            \
      const int o = (p * 256 + t) * 16;                                        \
      vpre[p] = *(const s16x8*)(vbase + (o >> 7) * 2048 + (KB) + ((o & 127) >> 1)); \
    }                                                                          \
  }
#define WRITEK()                                                               \
  {                                                                            \
    char* kdst = Ks + krow * 384;                                              \
    const int swk = (krow & 7) << 4;                                           \
    _Pragma("unroll") for (int j = 0; j < 6; ++j)                              \
        *(s16x8*)(kdst + ((kq * 16 + 64 * j) ^ swk)) = kpre[j];                \
    _Pragma("unroll") for (int p = 0; p < 4; ++p) {                            \
      const int o = (p * 256 + t) * 16;                                        \
      const int d = o >> 7, cb = o & 127;                                      \
      *(s16x8*)(Vs + d * 128 + (cb ^ ((d & 7) << 4))) = vpre[p];               \
    }                                                                          \
  }

  LOADK(kb0);
  WRITEK();
  __syncthreads();

  for (int it = 0; it < nt; ++it) {
    const int kb = kb0 + (it << 6);
    const bool havenext = (it + 1 < nt);
    if (havenext) LOADK(kb + 64);  // T14: issue early, hide under compute

    if (kb + 63 >= w0 - 1023 && kb <= w0 + 31) {  // wave participates
      const bool interior = (kb >= w0 - 992) && (kb <= w0 - 63);

      // QK^T (swapped): D[key][q], two 32-key blocks, K=192 via 12 e-chunks
      f32x16 s0 = {}, s1 = {};
#pragma unroll
      for (int ec = 0; ec < 12; ++ec) {
        const int colb = ec * 32 + g2 * 16;
        const int r0 = l5, r1 = 32 + l5;
        s16x8 kf0 = *(const s16x8*)(Ks + r0 * 384 + (colb ^ ((r0 & 7) << 4)));
        s16x8 kf1 = *(const s16x8*)(Ks + r1 * 384 + (colb ^ ((r1 & 7) << 4)));
        s0 = mfma32(kf0, qf[ec], s0);
        s1 = mfma32(kf1, qf[ec], s1);
      }

      // mask (boundary tiles only) + lane-local online softmax for row l5
      if (!interior) {
#pragma unroll
        for (int r = 0; r < 16; ++r) {
          const int kl = (r & 3) + 8 * (r >> 2) + 4 * g2;
          const int k0g = kb + kl, k1g = kb + 32 + kl;
          if (k0g > qrow || k0g <= qrow - 1024) s0[r] = -1e30f;
          if (k1g > qrow || k1g <= qrow - 1024) s1[r] = -1e30f;
        }
      }
      float mt = -1e30f;
#pragma unroll
      for (int r = 0; r < 16; ++r) mt = fmaxf(mt, fmaxf(s0[r], s1[r]));
      mt = fmaxf(mt, __shfl_xor(mt, 32));
      const float mn = fmaxf(m_r, mt);
      const float al = __expf(m_r - mn);
      m_r = mn;
      float p0[16], p1[16];
      float ps = 0.f;
#pragma unroll
      for (int r = 0; r < 16; ++r) {
        p0[r] = __expf(s0[r] - mn);
        p1[r] = __expf(s1[r] - mn);
        ps += p0[r] + p1[r];
      }
      ps += __shfl_xor(ps, 32);
      l_r = l_r * al + ps;
#pragma unroll
      for (int db = 0; db < 4; ++db) O[db] = O[db] * al;

      // P B-frags: sigma (key bits 2<->3) makes them consecutive own-lane regs
      s16x8 pf[4];
#pragma unroll
      for (int kc = 0; kc < 4; ++kc) {
#pragma unroll
        for (int j = 0; j < 8; ++j) {
          const float pv = (kc < 2) ? p0[8 * (kc & 1) + j] : p1[8 * (kc & 1) + j];
          pf[kc][j] = (short)f2bf(pv);
        }
      }

      // PV (swapped): D[d][q]; A = V^T with sigma-permuted key reads (2xb64)
#pragma unroll
      for (int db = 0; db < 4; ++db) {
#pragma unroll
        for (int kc = 0; kc < 4; ++kc) {
          const int d = db * 32 + l5;
          const int swv = (d & 7) << 4;
          const int c0 = kc * 32 + 8 * g2;
          s16x4 lo = *(const s16x4*)(Vs + d * 128 + (c0 ^ swv));
          s16x4 hi = *(const s16x4*)(Vs + d * 128 + ((c0 + 16) ^ swv));
          s16x8 vf = {lo[0], lo[1], lo[2], lo[3], hi[0], hi[1], hi[2], hi[3]};
          O[db] = mfma32(vf, pf[kc], O[db]);
        }
      }
    }

    __syncthreads();            // all waves done reading LDS tile it
    if (havenext) WRITEK();     // vmcnt wait inserted by compiler
    __syncthreads();            // next tile visible
  }

  // epilogue: O[d][q=l5], normalize by own-lane 1/l_r; paired u32 stores
  const float linv = 1.0f / l_r;
  unsigned short* ob = Ob + ((unsigned)(b * 2048 + qrow)) * 2048 + h * 128;
#pragma unroll
  for (int db = 0; db < 4; ++db) {
#pragma unroll
    for (int r = 0; r < 16; r += 2) {
      const int d = db * 32 + (r & 3) + 8 * (r >> 2) + 4 * g2;
      const unsigned int uo = (unsigned int)f2bf(O[db][r] * linv) |
                              ((unsigned int)f2bf(O[db][r + 1] * linv) << 16);
      *(unsigned int*)(ob + d) = uo;
    }
  }
}

extern "C" void kernel_launch(void* const* d_in, const int* in_sizes, int n_in,
                              void* d_out, int out_size, void* d_ws, size_t ws_size,
                              hipStream_t stream) {
  (void)in_sizes; (void)n_in; (void)out_size;
  const float* x    = (const float*)d_in[0];
  const float* cosp = (const float*)d_in[1];
  const float* sinp = (const float*)d_in[2];
  // d_in[3]=positions, d_in[4]=mask: dead
  const float* wq = (const float*)d_in[5];
  const float* wk = (const float*)d_in[6];
  const float* wv = (const float*)d_in[7];
  const float* wo = (const float*)d_in[8];
  float* out = (float*)d_out;

  if (ws_size < 25165824u) {
    k_sentinel<<<2048, 256, 0, stream>>>(out, 8388608);
    return;
  }

  char* ws = (char*)d_ws;
  unsigned short* xb  = (unsigned short*)(ws);             // 16 MiB; later attn_out
  unsigned short* wsl = (unsigned short*)(ws + 16777216);  // 8 MiB weight slot

  // d_out scratch: Q 16 MiB | K' 6 MiB | VT 4 MiB  (<= 26 MiB of 32)
  char* oc = (char*)d_out;
  unsigned short* Qb  = (unsigned short*)(oc);             // [2][16][2048][128]
  unsigned short* Kp  = (unsigned short*)(oc + 16777216);  // [2][4][2048][192]
  unsigned short* VTb = (unsigned short*)(oc + 23068672);  // [2][4][128][2048]

  k_cvt_x<<<2048, 256, 0, stream>>>(x, xb, 2097152);
  k_cvt_w<<<dim3(32, 32), 256, 0, stream>>>(wq, wsl, 2048, 1);
  k_gemm<<<dim3(32, 16), 256, 0, stream>>>(xb, wsl, 0, Qb, Kp, VTb, nullptr,
                                           cosp, sinp);
  k_cvt_w<<<dim3(8, 32), 256, 0, stream>>>(wk, wsl, 512, 0);
  k_cvt_w<<<dim3(8, 32), 256, 0, stream>>>(wv, wsl + 1048576, 512, 0);
  k_gemm<<<dim3(32, 8), 256, 0, stream>>>(xb, wsl, 1, Qb, Kp, VTb, nullptr,
                                          cosp, sinp);
  k_cvt_w<<<dim3(32, 32), 256, 0, stream>>>(wo, wsl, 2048, 0);
  k_attn<<<dim3(16, 16, 2), 256, 0, stream>>>(Qb, Kp, VTb, cosp, sinp, xb);
  k_gemm<<<dim3(32, 16), 256, 0, stream>>>(xb, wsl, 2, nullptr, nullptr, nullptr,
                                           out, nullptr, nullptr);
}